// Round 4
// baseline (429.606 us; speedup 1.0000x reference)
//
#include <hip/hip_runtime.h>

// VectorQuantizer: N=262144 rows, D=64 dims, K=512 codewords, fp32.
// out layout (floats): [0,N) idx ; [N, N+N*D) quantized_st ; [N+N*D] vq_loss
//
// CORRECTNESS MODEL (verified R2/R3, absmax 0): reproduce the np reference's
// fp32 bit pattern: d2 = fl(fl(x2 - fl(2*m)) + w2); x2/w2 via numpy
// pairwise-8 summation order; m = sequential FMA chain over d ascending
// (BLAS order); argmin strict < with lowest-index tie-break. All critical ops
// __fmul_rn/__fadd_rn/__fmaf_rn (no contraction/reassociation).
//
// R4 structure: thread owns a CODEWORD (w[c] resident in 64 VGPRs — divergent
// loads cannot be rematerialized, unlike R2/R3 where the compiler kept
// reloading the x row). Rows stream through as block-uniform broadcast loads.
// Bit-exact by construction; argmin via LDS d2 tile + exact reduce.
#define NROWS 262144
#define DDIM  64
#define KCB   512
#define BLOCK 512   // 8 waves; thread t owns codeword c = t
#define RPB   128   // rows per block  -> grid 2048
#define BATCH 16    // rows per LDS d2 tile batch
#define GRP   4     // rows in flight per thread (indep FMA chains)

// numpy FLOAT_pairwise_sum order for n=64 over terms fl(a[i]*a[i])
__device__ __forceinline__ float np_sumsq64(const float* a) {
    float r[8];
#pragma unroll
    for (int j = 0; j < 8; ++j) r[j] = __fmul_rn(a[j], a[j]);
#pragma unroll
    for (int i = 8; i < 64; i += 8) {
#pragma unroll
        for (int j = 0; j < 8; ++j)
            r[j] = __fadd_rn(r[j], __fmul_rn(a[i + j], a[i + j]));
    }
    return __fadd_rn(__fadd_rn(__fadd_rn(r[0], r[1]), __fadd_rn(r[2], r[3])),
                     __fadd_rn(__fadd_rn(r[4], r[5]), __fadd_rn(r[6], r[7])));
}

__launch_bounds__(BLOCK, 4)   // cap 128 VGPR: need ~95 (64 w + staging + acc)
__global__ void vq_main(const float* __restrict__ x,
                        const float* __restrict__ w,
                        float* __restrict__ out_idx) {
    const int tid = threadIdx.x;
    const int c   = tid;                    // codeword owned by this thread
    const int rowBase = blockIdx.x * RPB;

    __shared__ float d2tile[BATCH][KCB];    // 32 KB
    __shared__ float x2buf[BATCH];

    // ---- one-time: this thread's codeword into registers + its w2 ----
    float wl[DDIM];
    {
        const float4* wp = (const float4*)(w + (size_t)c * DDIM);
#pragma unroll
        for (int j = 0; j < 16; ++j) {
            float4 v = wp[j];
            wl[4 * j + 0] = v.x; wl[4 * j + 1] = v.y;
            wl[4 * j + 2] = v.z; wl[4 * j + 3] = v.w;
        }
    }
    const float w2l = np_sumsq64(wl);       // numpy order (R2-verified)

    for (int b = 0; b < RPB / BATCH; ++b) {
        const int r0 = rowBase + b * BATCH;

        // ---- x2 for BATCH rows: 8 threads/row, numpy pairwise-8 order ----
        // thread j of a row computes r[j] = sum_i fl(a[8i+j]^2) (i ascending),
        // then exact tree ((r0+r1)+(r2+r3))+((r4+r5)+(r6+r7)) via shfl_xor.
        if (tid < BATCH * 8) {
            const int rl = tid >> 3, j = tid & 7;
            const float* xr = x + (size_t)(r0 + rl) * DDIM;
            float a0 = xr[j];
            float r = __fmul_rn(a0, a0);
#pragma unroll
            for (int i = 1; i < 8; ++i) {
                float ai = xr[8 * i + j];
                r = __fadd_rn(r, __fmul_rn(ai, ai));
            }
            float s1 = __fadd_rn(r,  __shfl_xor(r, 1));
            float s2 = __fadd_rn(s1, __shfl_xor(s1, 2));
            float s4 = __fadd_rn(s2, __shfl_xor(s2, 4));
            if (j == 0) x2buf[rl] = s4;
        }
        __syncthreads();

        // ---- main: GRP rows in flight; block-uniform broadcast x loads ----
        for (int g = 0; g < BATCH; g += GRP) {
            const float* xr0 = x + (size_t)(r0 + g + 0) * DDIM;
            const float* xr1 = x + (size_t)(r0 + g + 1) * DDIM;
            const float* xr2 = x + (size_t)(r0 + g + 2) * DDIM;
            const float* xr3 = x + (size_t)(r0 + g + 3) * DDIM;
            float m0 = 0.f, m1 = 0.f, m2 = 0.f, m3 = 0.f;
#pragma unroll
            for (int jb = 0; jb < 16; ++jb) {
                float4 a0 = *(const float4*)(xr0 + 4 * jb);
                float4 a1 = *(const float4*)(xr1 + 4 * jb);
                float4 a2 = *(const float4*)(xr2 + 4 * jb);
                float4 a3 = *(const float4*)(xr3 + 4 * jb);
                // BLAS-order sequential chain per row: d ascending
                m0 = __fmaf_rn(a0.x, wl[4 * jb + 0], m0);
                m0 = __fmaf_rn(a0.y, wl[4 * jb + 1], m0);
                m0 = __fmaf_rn(a0.z, wl[4 * jb + 2], m0);
                m0 = __fmaf_rn(a0.w, wl[4 * jb + 3], m0);
                m1 = __fmaf_rn(a1.x, wl[4 * jb + 0], m1);
                m1 = __fmaf_rn(a1.y, wl[4 * jb + 1], m1);
                m1 = __fmaf_rn(a1.z, wl[4 * jb + 2], m1);
                m1 = __fmaf_rn(a1.w, wl[4 * jb + 3], m1);
                m2 = __fmaf_rn(a2.x, wl[4 * jb + 0], m2);
                m2 = __fmaf_rn(a2.y, wl[4 * jb + 1], m2);
                m2 = __fmaf_rn(a2.z, wl[4 * jb + 2], m2);
                m2 = __fmaf_rn(a2.w, wl[4 * jb + 3], m2);
                m3 = __fmaf_rn(a3.x, wl[4 * jb + 0], m3);
                m3 = __fmaf_rn(a3.y, wl[4 * jb + 1], m3);
                m3 = __fmaf_rn(a3.z, wl[4 * jb + 2], m3);
                m3 = __fmaf_rn(a3.w, wl[4 * jb + 3], m3);
            }
            // d2 = fl(fl(x2 - fl(2*m)) + w2); store to LDS tile at col c=tid
            float X0 = x2buf[g + 0], X1 = x2buf[g + 1];
            float X2 = x2buf[g + 2], X3 = x2buf[g + 3];
            d2tile[g + 0][c] = __fadd_rn(__fsub_rn(X0, __fmul_rn(2.0f, m0)), w2l);
            d2tile[g + 1][c] = __fadd_rn(__fsub_rn(X1, __fmul_rn(2.0f, m1)), w2l);
            d2tile[g + 2][c] = __fadd_rn(__fsub_rn(X2, __fmul_rn(2.0f, m2)), w2l);
            d2tile[g + 3][c] = __fadd_rn(__fsub_rn(X3, __fmul_rn(2.0f, m3)), w2l);
        }
        __syncthreads();

        // ---- exact argmin per row: 32 threads/row, 16 codewords each ----
        {
            const int rl  = tid >> 5;   // 0..15
            const int sub = tid & 31;
            float bv = d2tile[rl][sub];
            int   bi = sub;
#pragma unroll
            for (int i = 1; i < 16; ++i) {
                int cc = sub + 32 * i;      // ascending within thread subset
                float v = d2tile[rl][cc];
                if (v < bv) { bv = v; bi = cc; }   // strict < keeps lowest
            }
            // reduce across the 32 threads of this row (xor 1..16 stays
            // within the 32-lane half owning row rl)
#pragma unroll
            for (int s = 1; s < 32; s <<= 1) {
                float ov = __shfl_xor(bv, s);
                int   oi = __shfl_xor(bi, s);
                if (ov < bv || (ov == bv && oi < bi)) { bv = ov; bi = oi; }
            }
            if (sub == 0) out_idx[r0 + rl] = (float)bi;
        }
        __syncthreads();
    }
}

// ---- epilogue: gather codeword, quantized_st = fl(x + fl(q-x)), loss ----
__launch_bounds__(256)
__global__ void vq_epilogue(const float* __restrict__ x,
                            const float* __restrict__ w,
                            const float* __restrict__ out_idx_f,
                            float* __restrict__ out_q,
                            float* __restrict__ out_loss) {
    const int row  = blockIdx.x * blockDim.x + threadIdx.x;
    const int bidx = (int)out_idx_f[row];

    const float4* xp = (const float4*)(x + (size_t)row * DDIM);
    const float4* wq = (const float4*)(w + (size_t)bidx * DDIM);
    float4* qo = (float4*)(out_q + (size_t)row * DDIM);
    float ls = 0.0f;
#pragma unroll
    for (int j = 0; j < 16; ++j) {
        float4 xv = xp[j];
        float4 wv = wq[j];
        float e0 = __fsub_rn(wv.x, xv.x), e1 = __fsub_rn(wv.y, xv.y);
        float e2 = __fsub_rn(wv.z, xv.z), e3 = __fsub_rn(wv.w, xv.w);
        ls = fmaf(e0, e0, ls); ls = fmaf(e1, e1, ls);
        ls = fmaf(e2, e2, ls); ls = fmaf(e3, e3, ls);
        float4 q;
        q.x = __fadd_rn(xv.x, e0); q.y = __fadd_rn(xv.y, e1);
        q.z = __fadd_rn(xv.z, e2); q.w = __fadd_rn(xv.w, e3);
        qo[j] = q;
    }

#pragma unroll
    for (int off = 32; off > 0; off >>= 1) ls += __shfl_down(ls, off);
    __shared__ float red[4];
    const int lane = threadIdx.x & 63;
    const int wid  = threadIdx.x >> 6;
    if (lane == 0) red[wid] = ls;
    __syncthreads();
    if (threadIdx.x == 0) {
        float t = (red[0] + red[1]) + (red[2] + red[3]);
        // vq_loss = (1 + BETA) * mean((q-x)^2), BETA=0.25
        atomicAdd(out_loss, t * (1.25f / (float)(NROWS * DDIM)));
    }
}

extern "C" void kernel_launch(void* const* d_in, const int* in_sizes, int n_in,
                              void* d_out, int out_size, void* d_ws, size_t ws_size,
                              hipStream_t stream) {
    const float* x = (const float*)d_in[0];   // encoding [N, 64]
    const float* w = (const float*)d_in[1];   // weight   [512, 64]

    float* out      = (float*)d_out;
    float* out_idx  = out;                                        // N floats
    float* out_q    = out + (size_t)NROWS;                        // N*D floats
    float* out_loss = out + (size_t)NROWS + (size_t)NROWS * DDIM; // 1 float

    // loss slot must start at 0 (d_out is poisoned before each launch)
    hipMemsetAsync(out_loss, 0, sizeof(float), stream);

    vq_main<<<NROWS / RPB, BLOCK, 0, stream>>>(x, w, out_idx);
    vq_epilogue<<<NROWS / 256, 256, 0, stream>>>(x, w, out_idx, out_q, out_loss);
}